// Round 1
// baseline (130.698 us; speedup 1.0000x reference)
//
#include <hip/hip_runtime.h>

#define B_    64
#define C_    23
#define E_    1024
#define D_    1024
#define BOT_  128
#define BINS_ 8192
#define S_    3
#define NUMBINS (C_*BINS_)

typedef float f32x4 __attribute__((ext_vector_type(4)));

// ws layout (floats):
// [0,384)            M  : M[s*128+k]   = sum_d Wfc[s][d]      * Wb[d][k]
// [512,512+3072)     N  : N[s*1024+e]  = sum_d Wfc[s][1024+d] * We[d][e]
// [3584,3587)        c0 : c0[s] = sum_d Wfc[s][1024+d]*be[d] + bfc[s]
// [3600,3600+4416)   pe : pe[(b*C+c)*3+s] = eos_emb[b,c]·N[s] + c0[s]
#define WS_M  0
#define WS_N  512
#define WS_C0 3584
#define WS_PE 3600

__global__ __launch_bounds__(256) void kprep(const float* __restrict__ Wb,
                                             const float* __restrict__ We,
                                             const float* __restrict__ be,
                                             const float* __restrict__ Wfc,
                                             const float* __restrict__ bfc,
                                             float* __restrict__ ws) {
    int g = blockIdx.x * 256 + threadIdx.x;
    if (g < 384) {
        int s = g >> 7, k = g & 127;
        const float* w1 = Wfc + s * 2 * D_;
        float acc = 0.f;
        #pragma unroll 8
        for (int d = 0; d < D_; d++) acc += w1[d] * Wb[d * BOT_ + k];
        ws[WS_M + g] = acc;
    } else if (g < 384 + 3072) {
        int h = g - 384;
        int s = h >> 10, e = h & 1023;
        const float* w2 = Wfc + s * 2 * D_ + D_;
        float acc = 0.f;
        #pragma unroll 8
        for (int d = 0; d < D_; d++) acc += w2[d] * We[d * E_ + e];
        ws[WS_N + h] = acc;
    } else if (g < 384 + 3072 + 3) {
        int s = g - (384 + 3072);
        const float* w2 = Wfc + s * 2 * D_ + D_;
        float acc = 0.f;
        #pragma unroll 8
        for (int d = 0; d < D_; d++) acc += w2[d] * be[d];
        ws[WS_C0 + s] = acc + bfc[s];
    }
}

// one wave per (b,c) row: pe = eos_emb[row]·N[s] + c0[s]
__global__ __launch_bounds__(256) void kpe(const float* __restrict__ eos,
                                           float* ws) {
    int wave = threadIdx.x >> 6;
    int lane = threadIdx.x & 63;
    int row  = blockIdx.x * 4 + wave;      // 0..B*C-1 (=1471), grid covers exactly
    const float* x  = eos + (size_t)row * E_;
    const float* N0 = ws + WS_N;
    float a0 = 0.f, a1 = 0.f, a2 = 0.f;
    #pragma unroll
    for (int j = 0; j < E_ / 64; j++) {
        int i = lane + j * 64;
        float v = x[i];
        a0 += v * N0[i];
        a1 += v * N0[1024 + i];
        a2 += v * N0[2048 + i];
    }
    #pragma unroll
    for (int off = 32; off; off >>= 1) {
        a0 += __shfl_down(a0, off);
        a1 += __shfl_down(a1, off);
        a2 += __shfl_down(a2, off);
    }
    if (lane == 0) {
        float* pe = ws + WS_PE + row * 3;
        pe[0] = a0 + ws[WS_C0 + 0];
        pe[1] = a1 + ws[WS_C0 + 1];
        pe[2] = a2 + ws[WS_C0 + 2];
    }
}

// grid (32, 23): block = (c=blockIdx.y, n-chunk of 256 = blockIdx.x)
__global__ __launch_bounds__(256) void kmain(const float* __restrict__ table,
                                             const float* __restrict__ ws,
                                             float* __restrict__ out) {
    const int t  = threadIdx.x;
    const int c  = blockIdx.y;
    const int n0 = blockIdx.x * 256;

    __shared__ float Ml[384];    // M[s*128+k]
    __shared__ float pbl[768];   // pb[n_local*3+s]
    __shared__ float pel[192];   // pe[b*3+s] for this c

    for (int i = t; i < 384; i += 256) Ml[i] = ws[WS_M + i];
    if (t < 192) {
        int b = t / 3, s = t - b * 3;
        pel[t] = ws[WS_PE + (b * C_ + c) * 3 + s];
    }
    __syncthreads();

    // phase 1: pb[t][s] = table row (1 + c*BINS + n0 + t) · M[s]
    const f32x4* row = (const f32x4*)(table + (size_t)(1 + c * BINS_ + n0 + t) * BOT_);
    float a0 = 0.f, a1 = 0.f, a2 = 0.f;
    #pragma unroll 8
    for (int k4 = 0; k4 < 32; k4++) {
        f32x4 v = row[k4];
        int k = k4 * 4;
        a0 += v.x * Ml[k]       + v.y * Ml[k + 1]   + v.z * Ml[k + 2]   + v.w * Ml[k + 3];
        a1 += v.x * Ml[128 + k] + v.y * Ml[129 + k] + v.z * Ml[130 + k] + v.w * Ml[131 + k];
        a2 += v.x * Ml[256 + k] + v.y * Ml[257 + k] + v.z * Ml[258 + k] + v.w * Ml[259 + k];
    }
    pbl[t * 3 + 0] = a0;
    pbl[t * 3 + 1] = a1;
    pbl[t * 3 + 2] = a2;
    __syncthreads();

    // phase 2: for each b, write relu(pb + pe) as contiguous float4s
    if (t < 192) {
        f32x4 pv = *(const f32x4*)&pbl[t * 4];
        int s0 = t % 3;                 // (4t)%3 == t%3
        int s1 = (s0 + 1 == 3) ? 0 : s0 + 1;
        int s2 = (s1 + 1 == 3) ? 0 : s1 + 1;
        for (int b = 0; b < B_; b++) {
            const float* pe = &pel[b * 3];
            f32x4 o;
            o.x = fmaxf(pv.x + pe[s0], 0.f);
            o.y = fmaxf(pv.y + pe[s1], 0.f);
            o.z = fmaxf(pv.z + pe[s2], 0.f);
            o.w = fmaxf(pv.w + pe[s0], 0.f);
            f32x4* dst = (f32x4*)(out + ((size_t)(b * C_ + c) * BINS_ + n0) * 3) + t;
            __builtin_nontemporal_store(o, dst);
        }
    }
}

extern "C" void kernel_launch(void* const* d_in, const int* in_sizes, int n_in,
                              void* d_out, int out_size, void* d_ws, size_t ws_size,
                              hipStream_t stream) {
    const float* eos   = (const float*)d_in[0];
    const float* table = (const float*)d_in[1];
    const float* Wb    = (const float*)d_in[2];
    const float* We    = (const float*)d_in[3];
    const float* be    = (const float*)d_in[4];
    const float* Wfc   = (const float*)d_in[5];
    const float* bfc   = (const float*)d_in[6];
    float* out = (float*)d_out;
    float* ws  = (float*)d_ws;

    kprep<<<14, 256, 0, stream>>>(Wb, We, be, Wfc, bfc, ws);
    kpe<<<368, 256, 0, stream>>>(eos, ws);
    dim3 g(32, 23);
    kmain<<<g, 256, 0, stream>>>(table, ws, out);
}

// Round 2
// 59.237 us; speedup vs baseline: 2.2063x; 2.2063x over previous
//
#include <hip/hip_runtime.h>

#define B_    64
#define C_    23
#define E_    1024
#define D_    1024
#define BOT_  128
#define BINS_ 8192
#define S_    3
#define NUMBINS (C_*BINS_)

typedef float f32x4 __attribute__((ext_vector_type(4)));

// ws layout (floats):
// [0,384)            M  : M[s*128+k]   = sum_d Wfc[s][d]      * Wb[d][k]
// [512,512+3072)     N  : N[s*1024+e]  = sum_d Wfc[s][1024+d] * We[d][e]
// [3584,3587)        c0 : c0[s] = sum_d Wfc[s][1024+d]*be[d] + bfc[s]
// [3600,3600+4416)   pe : pe[(b*C+c)*3+s] = eos_emb[b,c]·N[s] + c0[s]
#define WS_M  0
#define WS_N  512
#define WS_C0 3584
#define WS_PE 3600

// grid: [0,96)  : N  (s = bx/32, e0 = (bx%32)*32)
//       [96,108): M  (m = bx-96, s = m/4, k0 = (m%4)*32)
//       108     : c0
// block 256 = 8 dgrp x 32 outputs; d-chain length 128, LDS tree reduce.
__global__ __launch_bounds__(256) void kprep(const float* __restrict__ Wb,
                                             const float* __restrict__ We,
                                             const float* __restrict__ be,
                                             const float* __restrict__ Wfc,
                                             const float* __restrict__ bfc,
                                             float* __restrict__ ws) {
    const int bx = blockIdx.x;
    const int t  = threadIdx.x;

    if (bx == 96 + 12) {           // c0
        int wave = t >> 6, lane = t & 63;
        if (wave < 3) {
            const float* w2 = Wfc + wave * 2 * D_ + D_;
            float acc = 0.f;
            #pragma unroll
            for (int j = 0; j < D_ / 64; j++) {
                int d = lane + j * 64;
                acc += w2[d] * be[d];
            }
            #pragma unroll
            for (int off = 32; off; off >>= 1) acc += __shfl_down(acc, off);
            if (lane == 0) ws[WS_C0 + wave] = acc + bfc[wave];
        }
        return;
    }

    __shared__ float wv[1024];     // broadcast vector (w1 or w2)
    __shared__ float red[256];

    const int og   = t & 31;       // output within the 32-chunk
    const int dgrp = t >> 5;       // 0..7, each owns 128 d's

    const float* src;              // matrix
    const float* wrow;             // broadcast row of Wfc
    int ostride, obase;            // src index = d*ostride + obase + og
    float* dst;

    if (bx < 96) {                 // N[s][e0+og]
        int s = bx >> 5, e0 = (bx & 31) * 32;
        src = We; ostride = E_; obase = e0;
        wrow = Wfc + s * 2 * D_ + D_;
        dst = ws + WS_N + s * E_ + e0;
    } else {                       // M[s][k0+og]
        int m = bx - 96;
        int s = m >> 2, k0 = (m & 3) * 32;
        src = Wb; ostride = BOT_; obase = k0;
        wrow = Wfc + s * 2 * D_;
        dst = ws + WS_M + s * BOT_ + k0;
    }

    for (int i = t; i < 1024; i += 256) wv[i] = wrow[i];
    __syncthreads();

    const float* p = src + (size_t)(dgrp * 128) * ostride + obase + og;
    const float* w = wv + dgrp * 128;
    float acc = 0.f;
    #pragma unroll 8
    for (int i = 0; i < 128; i++) {
        acc += w[i] * p[(size_t)i * ostride];
    }
    red[t] = acc;
    #pragma unroll
    for (int off = 128; off >= 32; off >>= 1) {
        __syncthreads();
        if (t < off) red[t] += red[t + off];
    }
    if (t < 32) dst[t] = red[t];
}

// one wave per (b,c) row: pe = eos_emb[row]·N[s] + c0[s]
__global__ __launch_bounds__(256) void kpe(const float* __restrict__ eos,
                                           float* ws) {
    int wave = threadIdx.x >> 6;
    int lane = threadIdx.x & 63;
    int row  = blockIdx.x * 4 + wave;      // 0..B*C-1 (=1471), grid covers exactly
    const float* x  = eos + (size_t)row * E_;
    const float* N0 = ws + WS_N;
    float a0 = 0.f, a1 = 0.f, a2 = 0.f;
    #pragma unroll
    for (int j = 0; j < E_ / 64; j++) {
        int i = lane + j * 64;
        float v = x[i];
        a0 += v * N0[i];
        a1 += v * N0[1024 + i];
        a2 += v * N0[2048 + i];
    }
    #pragma unroll
    for (int off = 32; off; off >>= 1) {
        a0 += __shfl_down(a0, off);
        a1 += __shfl_down(a1, off);
        a2 += __shfl_down(a2, off);
    }
    if (lane == 0) {
        float* pe = ws + WS_PE + row * 3;
        pe[0] = a0 + ws[WS_C0 + 0];
        pe[1] = a1 + ws[WS_C0 + 1];
        pe[2] = a2 + ws[WS_C0 + 2];
    }
}

// grid (32, 23): block = (c=blockIdx.y, n-chunk of 256 = blockIdx.x)
__global__ __launch_bounds__(256) void kmain(const float* __restrict__ table,
                                             const float* __restrict__ ws,
                                             float* __restrict__ out) {
    const int t  = threadIdx.x;
    const int c  = blockIdx.y;
    const int n0 = blockIdx.x * 256;

    __shared__ float Ml[384];    // M[s*128+k]
    __shared__ float pbl[768];   // pb[n_local*3+s]
    __shared__ float pel[192];   // pe[b*3+s] for this c

    for (int i = t; i < 384; i += 256) Ml[i] = ws[WS_M + i];
    if (t < 192) {
        int b = t / 3, s = t - b * 3;
        pel[t] = ws[WS_PE + (b * C_ + c) * 3 + s];
    }
    __syncthreads();

    // phase 1: pb[t][s] = table row (1 + c*BINS + n0 + t) · M[s]
    const f32x4* row = (const f32x4*)(table + (size_t)(1 + c * BINS_ + n0 + t) * BOT_);
    float a0 = 0.f, a1 = 0.f, a2 = 0.f;
    #pragma unroll 8
    for (int k4 = 0; k4 < 32; k4++) {
        f32x4 v = row[k4];
        int k = k4 * 4;
        a0 += v.x * Ml[k]       + v.y * Ml[k + 1]   + v.z * Ml[k + 2]   + v.w * Ml[k + 3];
        a1 += v.x * Ml[128 + k] + v.y * Ml[129 + k] + v.z * Ml[130 + k] + v.w * Ml[131 + k];
        a2 += v.x * Ml[256 + k] + v.y * Ml[257 + k] + v.z * Ml[258 + k] + v.w * Ml[259 + k];
    }
    pbl[t * 3 + 0] = a0;
    pbl[t * 3 + 1] = a1;
    pbl[t * 3 + 2] = a2;
    __syncthreads();

    // phase 2: for each b, write relu(pb + pe) as contiguous float4s
    if (t < 192) {
        f32x4 pv = *(const f32x4*)&pbl[t * 4];
        int s0 = t % 3;                 // (4t)%3 == t%3
        int s1 = (s0 + 1 == 3) ? 0 : s0 + 1;
        int s2 = (s1 + 1 == 3) ? 0 : s1 + 1;
        for (int b = 0; b < B_; b++) {
            const float* pe = &pel[b * 3];
            f32x4 o;
            o.x = fmaxf(pv.x + pe[s0], 0.f);
            o.y = fmaxf(pv.y + pe[s1], 0.f);
            o.z = fmaxf(pv.z + pe[s2], 0.f);
            o.w = fmaxf(pv.w + pe[s0], 0.f);
            f32x4* dst = (f32x4*)(out + ((size_t)(b * C_ + c) * BINS_ + n0) * 3) + t;
            __builtin_nontemporal_store(o, dst);
        }
    }
}

extern "C" void kernel_launch(void* const* d_in, const int* in_sizes, int n_in,
                              void* d_out, int out_size, void* d_ws, size_t ws_size,
                              hipStream_t stream) {
    const float* eos   = (const float*)d_in[0];
    const float* table = (const float*)d_in[1];
    const float* Wb    = (const float*)d_in[2];
    const float* We    = (const float*)d_in[3];
    const float* be    = (const float*)d_in[4];
    const float* Wfc   = (const float*)d_in[5];
    const float* bfc   = (const float*)d_in[6];
    float* out = (float*)d_out;
    float* ws  = (float*)d_ws;

    kprep<<<109, 256, 0, stream>>>(Wb, We, be, Wfc, bfc, ws);
    kpe<<<368, 256, 0, stream>>>(eos, ws);
    dim3 g(32, 23);
    kmain<<<g, 256, 0, stream>>>(table, ws, out);
}